// Round 1
// baseline (2844.670 us; speedup 1.0000x reference)
//
#include <hip/hip_runtime.h>
#include <math.h>

#define T_TOK 4096
#define HD    2048
#define NEXP  32
#define IR    1408
#define ISH   2816
#define NPAIR (T_TOK*4)

// ---------------------------------------------------------------- gate
__global__ __launch_bounds__(64) void gate_kernel(
    const float* __restrict__ x, const float* __restrict__ gw,
    int* __restrict__ topk_idx, float* __restrict__ topk_w, int* __restrict__ cnt)
{
  const int t = blockIdx.x;
  const int lane = threadIdx.x;
  const int e = lane & 31;
  const int half = lane >> 5;
  const float4* xr = (const float4*)(x  + (size_t)t*HD + half*(HD/2));
  const float4* wr = (const float4*)(gw + (size_t)e*HD + half*(HD/2));
  float p = 0.f;
  #pragma unroll 4
  for (int h = 0; h < HD/8; ++h) {
    float4 a = xr[h], b = wr[h];
    p += a.x*b.x + a.y*b.y + a.z*b.z + a.w*b.w;
  }
  p += __shfl_down(p, 32);
  float logit = (lane < 32) ? p : -INFINITY;
  float m = logit;
  #pragma unroll
  for (int o = 32; o >= 1; o >>= 1) m = fmaxf(m, __shfl_xor(m, o));
  float ex = (lane < 32) ? expf(logit - m) : 0.f;
  float se = ex;
  #pragma unroll
  for (int o = 32; o >= 1; o >>= 1) se += __shfl_xor(se, o);
  float score = ex / se;

  bool taken = false;
  float selw[4]; int seli[4];
  for (int k = 0; k < 4; ++k) {
    float cur = (lane < 32 && !taken) ? score : -1.f;
    float mm = cur;
    #pragma unroll
    for (int o = 32; o >= 1; o >>= 1) mm = fmaxf(mm, __shfl_xor(mm, o));
    unsigned long long b = __ballot(cur == mm);
    int il = __ffsll(b) - 1;
    if (lane == il) taken = true;
    selw[k] = mm; seli[k] = il;
  }
  float wsum = selw[0]+selw[1]+selw[2]+selw[3] + 1e-20f;
  if (lane < 4) {
    topk_idx[t*4+lane] = seli[lane];
    topk_w[t*4+lane]  = selw[lane] / wsum;
    atomicAdd(&cnt[seli[lane]], 1);
  }
}

// ---------------------------------------------------------------- scan
__global__ void scan_kernel(const int* __restrict__ cnt, int* __restrict__ offA)
{
  if (threadIdx.x == 0) {
    int a = 0;
    for (int e = 0; e < NEXP; ++e) { offA[e] = a; a += cnt[e]; }
    offA[NEXP] = a;
  }
}

// ---------------------------------------------------------------- scatter
__global__ __launch_bounds__(256) void scatter_kernel(
    const int* __restrict__ topk_idx, const float* __restrict__ topk_w,
    const int* __restrict__ offA, int* __restrict__ fill,
    int* __restrict__ list_tok, float* __restrict__ list_w)
{
  int t = blockIdx.x*256 + threadIdx.x;
  if (t >= T_TOK) return;
  #pragma unroll
  for (int k = 0; k < 4; ++k) {
    int e = topk_idx[t*4+k];
    int pos = atomicAdd(&fill[e], 1);
    int s = offA[e] + pos;
    list_tok[s] = t;
    list_w[s]  = topk_w[t*4+k];
  }
}

// ------------------------------------------------- R projections (4 GEMMs)
// Y[T,128] = X[T,2048] @ W[128,2048]^T ; grid.y picks (W,Y) pair.
__global__ __launch_bounds__(256) void rproj_kernel(
    const float* __restrict__ x,
    const float* __restrict__ Rg, const float* __restrict__ Ru,
    const float* __restrict__ sRg, const float* __restrict__ sRu,
    float* __restrict__ rg, float* __restrict__ ru,
    float* __restrict__ sa, float* __restrict__ su)
{
  __shared__ float xs[32][65];
  __shared__ float ws[128][65];
  const float* W; float* Y;
  switch (blockIdx.y) {
    case 0:  W = Rg;  Y = rg; break;
    case 1:  W = Ru;  Y = ru; break;
    case 2:  W = sRg; Y = sa; break;
    default: W = sRu; Y = su; break;
  }
  const int tid = threadIdx.x;
  const int r0 = blockIdx.x * 32;
  const int tg = tid >> 5, cg = tid & 31;
  float acc[4][4] = {{0.f}};
  for (int k0 = 0; k0 < HD; k0 += 64) {
    for (int li = tid; li < 32*64; li += 256) {
      int r = li >> 6, k = li & 63;
      xs[r][k] = x[(size_t)(r0 + r)*HD + k0 + k];
    }
    for (int li = tid; li < 128*64; li += 256) {
      int n = li >> 6, k = li & 63;
      ws[n][k] = W[(size_t)n*HD + k0 + k];
    }
    __syncthreads();
    #pragma unroll 4
    for (int k = 0; k < 64; ++k) {
      float a[4], b[4];
      #pragma unroll
      for (int i = 0; i < 4; ++i) a[i] = xs[tg*4+i][k];
      #pragma unroll
      for (int j = 0; j < 4; ++j) b[j] = ws[cg+32*j][k];
      #pragma unroll
      for (int i = 0; i < 4; ++i)
        #pragma unroll
        for (int j = 0; j < 4; ++j) acc[i][j] += a[i]*b[j];
    }
    __syncthreads();
  }
  #pragma unroll
  for (int i = 0; i < 4; ++i)
    #pragma unroll
    for (int j = 0; j < 4; ++j)
      Y[(size_t)(r0 + tg*4+i)*128 + cg + 32*j] = acc[i][j];
}

// ------------------------------------- shared helper: 32x128 @ 128x128^T
// Loads 32 gathered rows of src (row ids in rows[]) into dst, computes
// dst_new = loaded @ U^T, overwriting dst. stage must hold >= 128*65 floats.
__device__ __forceinline__ void small_gemm_128(
    int tid, int tg, int cg,
    const float* __restrict__ src, const int* __restrict__ rows,
    const float* __restrict__ U, float (*dst)[129], float* __restrict__ stage)
{
  for (int li = tid; li < 32*128; li += 256) {
    int r = li >> 7, k = li & 127;
    dst[r][k] = src[(size_t)rows[r]*128 + k];
  }
  __syncthreads();
  float acc[4][4] = {{0.f}};
  for (int kh = 0; kh < 2; ++kh) {
    for (int li = tid; li < 128*64; li += 256) {
      int n = li >> 6, kk = li & 63;
      stage[n*65 + kk] = U[(size_t)n*128 + kh*64 + kk];
    }
    __syncthreads();
    #pragma unroll 4
    for (int kk = 0; kk < 64; ++kk) {
      int k = kh*64 + kk;
      float a[4], b[4];
      #pragma unroll
      for (int i = 0; i < 4; ++i) a[i] = dst[tg*4+i][k];
      #pragma unroll
      for (int j = 0; j < 4; ++j) b[j] = stage[(cg+32*j)*65 + kk];
      #pragma unroll
      for (int i = 0; i < 4; ++i)
        #pragma unroll
        for (int j = 0; j < 4; ++j) acc[i][j] += a[i]*b[j];
    }
    __syncthreads();
  }
  #pragma unroll
  for (int i = 0; i < 4; ++i)
    #pragma unroll
    for (int j = 0; j < 4; ++j) dst[tg*4+i][cg+32*j] = acc[i][j];
  __syncthreads();
}

// ---------------------------------------------------------------- mid
// Per (expert-or-shared, 32-row tile): t1=rg@Ug^T, t2=ru@Uu^T (in LDS),
// then loop I tiles: g=silu(t1@Cg^T), u=t2@Cu^T, h=g*u, rd += h@Rd^T (regs).
__global__ __launch_bounds__(256) void mid_kernel(
    const float* __restrict__ rg, const float* __restrict__ ru,
    const float* __restrict__ sa, const float* __restrict__ su,
    const float* __restrict__ Ug, const float* __restrict__ Cg,
    const float* __restrict__ Uu, const float* __restrict__ Cu,
    const float* __restrict__ Rd,
    const float* __restrict__ sUg, const float* __restrict__ sCg,
    const float* __restrict__ sUu, const float* __restrict__ sCu,
    const float* __restrict__ sRd,
    const int* __restrict__ offA, const int* __restrict__ cntA,
    const int* __restrict__ list_tok,
    float* __restrict__ rdout, float* __restrict__ rdouts)
{
  __shared__ float t1s[32][129];
  __shared__ float t2s[32][129];
  __shared__ float hs[32][65];
  __shared__ float stage[8320];
  __shared__ int toks[32];

  const int tid = threadIdx.x;
  const int by = blockIdx.y;
  const bool shm = (by == NEXP);
  const int nrows = shm ? T_TOK : cntA[by];
  const int s0 = blockIdx.x * 32;
  if (s0 >= nrows) return;
  const int base = shm ? 0 : offA[by];
  const int Ifull = shm ? ISH : IR;
  const float* pUg = shm ? sUg : Ug + (size_t)by*128*128;
  const float* pCg = shm ? sCg : Cg + (size_t)by*IR*128;
  const float* pUu = shm ? sUu : Uu + (size_t)by*128*128;
  const float* pCu = shm ? sCu : Cu + (size_t)by*IR*128;
  const float* pRd = shm ? sRd : Rd;
  const float* pA = shm ? sa : rg;
  const float* pB = shm ? su : ru;
  const int tg = tid >> 5, cg = tid & 31;

  if (tid < 32) {
    int sc = s0 + tid; if (sc > nrows-1) sc = nrows-1;
    toks[tid] = shm ? sc : list_tok[base + sc];
  }
  __syncthreads();

  small_gemm_128(tid, tg, cg, pA, toks, pUg, t1s, stage);
  small_gemm_128(tid, tg, cg, pB, toks, pUu, t2s, stage);

  float rdacc[4][4] = {{0.f}};
  const int ntiles = Ifull >> 6;
  for (int it = 0; it < ntiles; ++it) {
    const int i0 = it << 6;
    // ---- stage Cg tile [64 i][128 k], compute g (regs), silu ----
    for (int li = tid; li < 64*128; li += 256) {
      int ii = li >> 7, k = li & 127;
      stage[ii*129 + k] = pCg[(size_t)(i0+ii)*128 + k];
    }
    __syncthreads();
    float gv[4][2] = {{0.f}};
    #pragma unroll 4
    for (int k = 0; k < 128; ++k) {
      float a[4], b[2];
      #pragma unroll
      for (int i = 0; i < 4; ++i) a[i] = t1s[tg*4+i][k];
      #pragma unroll
      for (int j = 0; j < 2; ++j) b[j] = stage[(cg+32*j)*129 + k];
      #pragma unroll
      for (int i = 0; i < 4; ++i)
        #pragma unroll
        for (int j = 0; j < 2; ++j) gv[i][j] += a[i]*b[j];
    }
    #pragma unroll
    for (int i = 0; i < 4; ++i)
      #pragma unroll
      for (int j = 0; j < 2; ++j) gv[i][j] = gv[i][j] / (1.f + expf(-gv[i][j]));
    __syncthreads();
    // ---- stage Cu tile, compute u, h = g*u -> LDS ----
    for (int li = tid; li < 64*128; li += 256) {
      int ii = li >> 7, k = li & 127;
      stage[ii*129 + k] = pCu[(size_t)(i0+ii)*128 + k];
    }
    __syncthreads();
    float uv[4][2] = {{0.f}};
    #pragma unroll 4
    for (int k = 0; k < 128; ++k) {
      float a[4], b[2];
      #pragma unroll
      for (int i = 0; i < 4; ++i) a[i] = t2s[tg*4+i][k];
      #pragma unroll
      for (int j = 0; j < 2; ++j) b[j] = stage[(cg+32*j)*129 + k];
      #pragma unroll
      for (int i = 0; i < 4; ++i)
        #pragma unroll
        for (int j = 0; j < 2; ++j) uv[i][j] += a[i]*b[j];
    }
    #pragma unroll
    for (int i = 0; i < 4; ++i)
      #pragma unroll
      for (int j = 0; j < 2; ++j) hs[tg*4+i][cg+32*j] = gv[i][j]*uv[i][j];
    __syncthreads();
    // ---- stage Rd tile [128 r][64 i], rd += h @ Rd^T ----
    for (int li = tid; li < 128*64; li += 256) {
      int r = li >> 6, ii = li & 63;
      stage[r*65 + ii] = pRd[(size_t)r*Ifull + i0 + ii];
    }
    __syncthreads();
    #pragma unroll 4
    for (int ii = 0; ii < 64; ++ii) {
      float h[4], b[4];
      #pragma unroll
      for (int i = 0; i < 4; ++i) h[i] = hs[tg*4+i][ii];
      #pragma unroll
      for (int j = 0; j < 4; ++j) b[j] = stage[(cg+32*j)*65 + ii];
      #pragma unroll
      for (int i = 0; i < 4; ++i)
        #pragma unroll
        for (int j = 0; j < 4; ++j) rdacc[i][j] += h[i]*b[j];
    }
    __syncthreads();
  }
  #pragma unroll
  for (int i = 0; i < 4; ++i) {
    int s = s0 + tg*4+i;
    if (s < nrows) {
      #pragma unroll
      for (int j = 0; j < 4; ++j) {
        if (shm) rdouts[(size_t)s*128 + cg+32*j] = rdacc[i][j];
        else     rdout[(size_t)(base+s)*128 + cg+32*j] = rdacc[i][j];
      }
    }
  }
}

// ---------------------------------------------------------------- out
// t3 = rd @ Ud^T (LDS), then y = t3 @ Cd^T, scaled by gate weight,
// atomicAdd into out (out pre-zeroed; shared expert = by==NEXP with w=1).
__global__ __launch_bounds__(256) void out_kernel(
    const float* __restrict__ rdbuf, const float* __restrict__ rdsbuf,
    const float* __restrict__ Ud, const float* __restrict__ Cd,
    const float* __restrict__ sUd, const float* __restrict__ sCd,
    const int* __restrict__ offA, const int* __restrict__ cntA,
    const int* __restrict__ list_tok, const float* __restrict__ list_w,
    float* __restrict__ out)
{
  __shared__ float t3s[32][129];
  __shared__ float stage[8320];
  __shared__ int   toks[32];
  __shared__ int   rowsrc[32];
  __shared__ float wrow[32];

  const int tid = threadIdx.x;
  const int by = blockIdx.y;
  const bool shm = (by == NEXP);
  const int nrows = shm ? T_TOK : cntA[by];
  const int s0 = blockIdx.x * 32;
  if (s0 >= nrows) return;
  const int base = shm ? 0 : offA[by];
  const int tg = tid >> 5, cg = tid & 31;

  if (tid < 32) {
    int sc = s0 + tid; if (sc > nrows-1) sc = nrows-1;
    rowsrc[tid] = base + sc;
    toks[tid] = shm ? sc : list_tok[base + sc];
    wrow[tid] = shm ? 1.f : list_w[base + sc];
  }
  __syncthreads();

  const float* rsrc = shm ? rdsbuf : rdbuf;
  const float* pUd = shm ? sUd : Ud + (size_t)by*128*128;
  const float* pCd = shm ? sCd : Cd + (size_t)by*HD*128;
  small_gemm_128(tid, tg, cg, rsrc, rowsrc, pUd, t3s, stage);

  for (int ct = 0; ct < HD/64; ++ct) {
    for (int li = tid; li < 64*128; li += 256) {
      int c = li >> 7, n = li & 127;
      stage[c*129 + n] = pCd[(size_t)(ct*64 + c)*128 + n];
    }
    __syncthreads();
    float y[4][2] = {{0.f}};
    #pragma unroll 4
    for (int n = 0; n < 128; ++n) {
      float a[4], b[2];
      #pragma unroll
      for (int i = 0; i < 4; ++i) a[i] = t3s[tg*4+i][n];
      #pragma unroll
      for (int j = 0; j < 2; ++j) b[j] = stage[(cg+32*j)*129 + n];
      #pragma unroll
      for (int i = 0; i < 4; ++i)
        #pragma unroll
        for (int j = 0; j < 2; ++j) y[i][j] += a[i]*b[j];
    }
    #pragma unroll
    for (int i = 0; i < 4; ++i) {
      int s = s0 + tg*4+i;
      if (s < nrows) {
        float wv = wrow[tg*4+i];
        size_t ob = (size_t)toks[tg*4+i]*HD + ct*64;
        atomicAdd(&out[ob + cg],      y[i][0]*wv);
        atomicAdd(&out[ob + cg + 32], y[i][1]*wv);
      }
    }
    __syncthreads();
  }
}

// ---------------------------------------------------------------- launch
extern "C" void kernel_launch(void* const* d_in, const int* in_sizes, int n_in,
                              void* d_out, int out_size, void* d_ws, size_t ws_size,
                              hipStream_t stream) {
  const float* x    = (const float*)d_in[0];
  const float* gw   = (const float*)d_in[1];
  const float* Rg   = (const float*)d_in[2];
  const float* Ru   = (const float*)d_in[3];
  const float* Rd   = (const float*)d_in[4];
  const float* Ug   = (const float*)d_in[5];
  const float* Cg   = (const float*)d_in[6];
  const float* Uu   = (const float*)d_in[7];
  const float* Cu   = (const float*)d_in[8];
  const float* Ud   = (const float*)d_in[9];
  const float* Cd   = (const float*)d_in[10];
  const float* sRg  = (const float*)d_in[11];
  const float* sUg  = (const float*)d_in[12];
  const float* sCg  = (const float*)d_in[13];
  const float* sRu  = (const float*)d_in[14];
  const float* sUu  = (const float*)d_in[15];
  const float* sCu  = (const float*)d_in[16];
  const float* sRd  = (const float*)d_in[17];
  const float* sUd  = (const float*)d_in[18];
  const float* sCd  = (const float*)d_in[19];
  float* out = (float*)d_out;

  char* w = (char*)d_ws;
  auto alloc = [&](size_t bytes) -> void* {
    void* p = (void*)w; w += (bytes + 255) & ~(size_t)255; return p;
  };
  int*   cnt      = (int*)  alloc(NEXP*sizeof(int));
  int*   offA     = (int*)  alloc((NEXP+1)*sizeof(int));
  int*   fill     = (int*)  alloc(NEXP*sizeof(int));
  int*   topk_idx = (int*)  alloc((size_t)T_TOK*4*sizeof(int));
  float* topk_w   = (float*)alloc((size_t)T_TOK*4*sizeof(float));
  int*   list_tok = (int*)  alloc((size_t)NPAIR*sizeof(int));
  float* list_w   = (float*)alloc((size_t)NPAIR*sizeof(float));
  float* rg       = (float*)alloc((size_t)T_TOK*128*sizeof(float));
  float* ru       = (float*)alloc((size_t)T_TOK*128*sizeof(float));
  float* sa       = (float*)alloc((size_t)T_TOK*128*sizeof(float));
  float* su       = (float*)alloc((size_t)T_TOK*128*sizeof(float));
  float* rdbuf    = (float*)alloc((size_t)NPAIR*128*sizeof(float));
  float* rdsbuf   = (float*)alloc((size_t)T_TOK*128*sizeof(float));
  (void)ws_size; (void)in_sizes; (void)n_in;

  hipMemsetAsync(cnt,  0, NEXP*sizeof(int), stream);
  hipMemsetAsync(fill, 0, NEXP*sizeof(int), stream);
  hipMemsetAsync(out,  0, (size_t)out_size*sizeof(float), stream);

  gate_kernel<<<T_TOK, 64, 0, stream>>>(x, gw, topk_idx, topk_w, cnt);
  scan_kernel<<<1, 64, 0, stream>>>(cnt, offA);
  scatter_kernel<<<T_TOK/256, 256, 0, stream>>>(topk_idx, topk_w, offA, fill, list_tok, list_w);
  rproj_kernel<<<dim3(T_TOK/32, 4), 256, 0, stream>>>(x, Rg, Ru, sRg, sRu, rg, ru, sa, su);
  mid_kernel<<<dim3(T_TOK/32, NEXP+1), 256, 0, stream>>>(
      rg, ru, sa, su, Ug, Cg, Uu, Cu, Rd, sUg, sCg, sUu, sCu, sRd,
      offA, cnt, list_tok, rdbuf, rdsbuf);
  out_kernel<<<dim3(T_TOK/32, NEXP+1), 256, 0, stream>>>(
      rdbuf, rdsbuf, Ud, Cd, sUd, sCd, offA, cnt, list_tok, list_w, out);
}

// Round 2
// 1196.000 us; speedup vs baseline: 2.3785x; 2.3785x over previous
//
#include <hip/hip_runtime.h>
#include <math.h>

#define T_TOK 4096
#define HD    2048
#define NEXP  32
#define IR    1408
#define ISH   2816
#define NPAIR (T_TOK*4)
#define SRK   136   // 128+8 bf16 LDS row stride (16B-aligned rows, 2-way-bank only)
#define SRH   72    // 64+8

typedef unsigned short ushort_t;
typedef __attribute__((ext_vector_type(8))) short    short8;
typedef __attribute__((ext_vector_type(8))) __bf16   bf16x8;
typedef __attribute__((ext_vector_type(4))) float    f32x4;

__device__ __forceinline__ f32x4 MF(short8 a, short8 b, f32x4 c) {
  return __builtin_amdgcn_mfma_f32_16x16x32_bf16(
      __builtin_bit_cast(bf16x8, a), __builtin_bit_cast(bf16x8, b), c, 0, 0, 0);
}
__device__ __forceinline__ ushort_t f2b(float f) {
  unsigned u = __float_as_uint(f);
  unsigned r = (u + 0x7fffu + ((u >> 16) & 1u)) >> 16;   // RNE
  return (ushort_t)r;
}

// ---------------------------------------------------------------- cvt fp32->bf16
__global__ __launch_bounds__(256) void cvt_kernel(
    const float* __restrict__ src, ushort_t* __restrict__ dst, int n4)
{
  int i = blockIdx.x*256 + threadIdx.x;
  if (i < n4) {
    float4 v = ((const float4*)src)[i];
    ushort4 o;
    o.x = f2b(v.x); o.y = f2b(v.y); o.z = f2b(v.z); o.w = f2b(v.w);
    ((ushort4*)dst)[i] = o;
  }
}

// ---------------------------------------------------------------- gate (fp32)
__global__ __launch_bounds__(64) void gate_kernel(
    const float* __restrict__ x, const float* __restrict__ gw,
    int* __restrict__ topk_idx, float* __restrict__ topk_w, int* __restrict__ cnt)
{
  const int t = blockIdx.x;
  const int lane = threadIdx.x;
  const int e = lane & 31;
  const int half = lane >> 5;
  const float4* xr = (const float4*)(x  + (size_t)t*HD + half*(HD/2));
  const float4* wr = (const float4*)(gw + (size_t)e*HD + half*(HD/2));
  float p = 0.f;
  #pragma unroll 4
  for (int h = 0; h < HD/8; ++h) {
    float4 a = xr[h], b = wr[h];
    p += a.x*b.x + a.y*b.y + a.z*b.z + a.w*b.w;
  }
  p += __shfl_down(p, 32);
  float logit = (lane < 32) ? p : -INFINITY;
  float m = logit;
  #pragma unroll
  for (int o = 32; o >= 1; o >>= 1) m = fmaxf(m, __shfl_xor(m, o));
  float ex = (lane < 32) ? expf(logit - m) : 0.f;
  float se = ex;
  #pragma unroll
  for (int o = 32; o >= 1; o >>= 1) se += __shfl_xor(se, o);
  float score = ex / se;

  bool taken = false;
  float selw[4]; int seli[4];
  for (int k = 0; k < 4; ++k) {
    float cur = (lane < 32 && !taken) ? score : -1.f;
    float mm = cur;
    #pragma unroll
    for (int o = 32; o >= 1; o >>= 1) mm = fmaxf(mm, __shfl_xor(mm, o));
    unsigned long long b = __ballot(cur == mm);
    int il = __ffsll(b) - 1;
    if (lane == il) taken = true;
    selw[k] = mm; seli[k] = il;
  }
  float wsum = selw[0]+selw[1]+selw[2]+selw[3] + 1e-20f;
  if (lane < 4) {
    topk_idx[t*4+lane] = seli[lane];
    topk_w[t*4+lane]  = selw[lane] / wsum;
    atomicAdd(&cnt[seli[lane]], 1);
  }
}

__global__ void scan_kernel(const int* __restrict__ cnt, int* __restrict__ offA)
{
  if (threadIdx.x == 0) {
    int a = 0;
    for (int e = 0; e < NEXP; ++e) { offA[e] = a; a += cnt[e]; }
    offA[NEXP] = a;
  }
}

__global__ __launch_bounds__(256) void scatter_kernel(
    const int* __restrict__ topk_idx, const float* __restrict__ topk_w,
    const int* __restrict__ offA, int* __restrict__ fill,
    int* __restrict__ list_tok, float* __restrict__ list_w)
{
  int t = blockIdx.x*256 + threadIdx.x;
  if (t >= T_TOK) return;
  #pragma unroll
  for (int k = 0; k < 4; ++k) {
    int e = topk_idx[t*4+k];
    int pos = atomicAdd(&fill[e], 1);
    int s = offA[e] + pos;
    list_tok[s] = t;
    list_w[s]  = topk_w[t*4+k];
  }
}

// ------------------------------------------------- R projections, bf16 MFMA
// Y[T,128] = Xb[T,2048] @ W[128,2048]^T, output bf16. grid (T/64, 4).
__global__ __launch_bounds__(256) void rproj_kernel(
    const ushort_t* __restrict__ xb,
    const ushort_t* __restrict__ Rg, const ushort_t* __restrict__ Ru,
    const ushort_t* __restrict__ sRg, const ushort_t* __restrict__ sRu,
    ushort_t* __restrict__ rg, ushort_t* __restrict__ ru,
    ushort_t* __restrict__ sa, ushort_t* __restrict__ su)
{
  __shared__ ushort_t As[64*SRK];
  __shared__ ushort_t Bs[128*SRK];
  const ushort_t* W; ushort_t* Y;
  switch (blockIdx.y) {
    case 0:  W = Rg;  Y = rg; break;
    case 1:  W = Ru;  Y = ru; break;
    case 2:  W = sRg; Y = sa; break;
    default: W = sRu; Y = su; break;
  }
  const int tid = threadIdx.x;
  const int lane = tid & 63, wv = tid >> 6;
  const int ln = lane & 15, q = lane >> 4;
  const int mh = wv >> 1, nh = wv & 1;
  const int r0 = blockIdx.x * 64;

  f32x4 acc[2][4];
  #pragma unroll
  for (int i = 0; i < 2; ++i)
    #pragma unroll
    for (int j = 0; j < 4; ++j) acc[i][j] = (f32x4){0.f,0.f,0.f,0.f};

  for (int k0 = 0; k0 < HD; k0 += 128) {
    for (int li = tid; li < 64*16; li += 256) {      // A tile 64x128
      int r = li >> 4, c = (li & 15) << 3;
      *(short8*)(As + r*SRK + c) = *(const short8*)(xb + (size_t)(r0+r)*HD + k0 + c);
    }
    for (int li = tid; li < 128*16; li += 256) {     // B tile 128x128
      int r = li >> 4, c = (li & 15) << 3;
      *(short8*)(Bs + r*SRK + c) = *(const short8*)(W + (size_t)r*HD + k0 + c);
    }
    __syncthreads();
    #pragma unroll
    for (int kk = 0; kk < 128; kk += 32) {
      short8 a[2], b[4];
      #pragma unroll
      for (int i = 0; i < 2; ++i)
        a[i] = *(const short8*)(As + (mh*32 + i*16 + ln)*SRK + kk + q*8);
      #pragma unroll
      for (int j = 0; j < 4; ++j)
        b[j] = *(const short8*)(Bs + (nh*64 + j*16 + ln)*SRK + kk + q*8);
      #pragma unroll
      for (int i = 0; i < 2; ++i)
        #pragma unroll
        for (int j = 0; j < 4; ++j) acc[i][j] = MF(a[i], b[j], acc[i][j]);
    }
    __syncthreads();
  }
  #pragma unroll
  for (int i = 0; i < 2; ++i)
    #pragma unroll
    for (int j = 0; j < 4; ++j)
      #pragma unroll
      for (int r = 0; r < 4; ++r)
        Y[(size_t)(r0 + mh*32 + i*16 + q*4 + r)*128 + nh*64 + j*16 + ln] = f2b(acc[i][j][r]);
}

// ------------------------- helper: Tout[64][SRK] = A_lds[64][SRK] @ Wg[128][128]^T
__device__ __forceinline__ void gemm_AxWT_128(
    int tid, const ushort_t* __restrict__ Wg,
    const ushort_t* __restrict__ A, ushort_t* __restrict__ stage,
    ushort_t* __restrict__ Tout)
{
  const int lane = tid & 63, wv = tid >> 6;
  const int ln = lane & 15, q = lane >> 4;
  const int mh = wv >> 1, nh = wv & 1;
  f32x4 acc[2][2][2];
  #pragma unroll
  for (int h = 0; h < 2; ++h)
    #pragma unroll
    for (int i = 0; i < 2; ++i)
      #pragma unroll
      for (int j = 0; j < 2; ++j) acc[h][i][j] = (f32x4){0.f,0.f,0.f,0.f};

  for (int h = 0; h < 2; ++h) {
    for (int li = tid; li < 64*16; li += 256) {
      int r = li >> 4, c = (li & 15) << 3;
      *(short8*)(stage + r*SRK + c) = *(const short8*)(Wg + (size_t)(h*64 + r)*128 + c);
    }
    __syncthreads();
    #pragma unroll
    for (int kk = 0; kk < 128; kk += 32) {
      short8 a[2], b[2];
      #pragma unroll
      for (int i = 0; i < 2; ++i)
        a[i] = *(const short8*)(A + (mh*32 + i*16 + ln)*SRK + kk + q*8);
      #pragma unroll
      for (int j = 0; j < 2; ++j)
        b[j] = *(const short8*)(stage + (nh*32 + j*16 + ln)*SRK + kk + q*8);
      #pragma unroll
      for (int i = 0; i < 2; ++i)
        #pragma unroll
        for (int j = 0; j < 2; ++j) acc[h][i][j] = MF(a[i], b[j], acc[h][i][j]);
    }
    __syncthreads();
  }
  #pragma unroll
  for (int h = 0; h < 2; ++h)
    #pragma unroll
    for (int i = 0; i < 2; ++i)
      #pragma unroll
      for (int j = 0; j < 2; ++j)
        #pragma unroll
        for (int r = 0; r < 4; ++r)
          Tout[(mh*32 + i*16 + q*4 + r)*SRK + h*64 + nh*32 + j*16 + ln] = f2b(acc[h][i][j][r]);
  __syncthreads();
}

// ---------------------------------------------------------------- mid (bf16 MFMA)
// grid (64, NEXP+1). Per (expert, 64-row tile): t1 = rows(rg)@Ug^T, t2 = rows(ru)@Uu^T,
// loop I-tiles of 64: g=silu(t1@Cg^T), u=t2@Cu^T, h=g*u (LDS), rd += h@Rd^T (regs).
__global__ __launch_bounds__(256) void mid_kernel(
    const ushort_t* __restrict__ rgb, const ushort_t* __restrict__ rub,
    const ushort_t* __restrict__ sab, const ushort_t* __restrict__ sub,
    const ushort_t* __restrict__ Ug, const ushort_t* __restrict__ Cg,
    const ushort_t* __restrict__ Uu, const ushort_t* __restrict__ Cu,
    const ushort_t* __restrict__ Rd,
    const ushort_t* __restrict__ sUg, const ushort_t* __restrict__ sCg,
    const ushort_t* __restrict__ sUu, const ushort_t* __restrict__ sCu,
    const ushort_t* __restrict__ sRd,
    const int* __restrict__ offA, const int* __restrict__ cntA,
    const int* __restrict__ list_tok,
    ushort_t* __restrict__ rdb, ushort_t* __restrict__ rdsb)
{
  __shared__ ushort_t ldsT1[64*SRK];
  __shared__ ushort_t ldsT2[64*SRK];
  __shared__ ushort_t ldsX [64*SRK];   // gather buffer, then h[64][SRH]
  __shared__ ushort_t ldsW [128*SRH];  // >= 64*SRK; staging for Ug/Cg/Cu/Rd tiles
  __shared__ int toks[64];

  const int tid = threadIdx.x;
  const int by = blockIdx.y;
  const bool shm = (by == NEXP);
  const int nrows = shm ? T_TOK : cntA[by];
  const int s0 = blockIdx.x * 64;
  if (s0 >= nrows) return;
  const int base = shm ? 0 : offA[by];
  const int Ifull = shm ? ISH : IR;
  const ushort_t* pUg = shm ? sUg : Ug + (size_t)by*128*128;
  const ushort_t* pCg = shm ? sCg : Cg + (size_t)by*IR*128;
  const ushort_t* pUu = shm ? sUu : Uu + (size_t)by*128*128;
  const ushort_t* pCu = shm ? sCu : Cu + (size_t)by*IR*128;
  const ushort_t* pRd = shm ? sRd : Rd;
  const ushort_t* pA  = shm ? sab : rgb;
  const ushort_t* pB  = shm ? sub : rub;

  const int lane = tid & 63, wv = tid >> 6;
  const int ln = lane & 15, q = lane >> 4;
  const int mh = wv >> 1, nh = wv & 1;

  if (tid < 64) {
    int sc = s0 + tid; if (sc > nrows-1) sc = nrows-1;
    toks[tid] = shm ? sc : list_tok[base + sc];
  }
  __syncthreads();

  // gather rg rows -> ldsX ; t1 = ldsX @ Ug^T
  for (int li = tid; li < 64*16; li += 256) {
    int r = li >> 4, c = (li & 15) << 3;
    *(short8*)(ldsX + r*SRK + c) = *(const short8*)(pA + (size_t)toks[r]*128 + c);
  }
  __syncthreads();
  gemm_AxWT_128(tid, pUg, ldsX, ldsW, ldsT1);

  // gather ru rows -> ldsX ; t2 = ldsX @ Uu^T
  for (int li = tid; li < 64*16; li += 256) {
    int r = li >> 4, c = (li & 15) << 3;
    *(short8*)(ldsX + r*SRK + c) = *(const short8*)(pB + (size_t)toks[r]*128 + c);
  }
  __syncthreads();
  gemm_AxWT_128(tid, pUu, ldsX, ldsW, ldsT2);

  f32x4 rdacc[2][4];
  #pragma unroll
  for (int i = 0; i < 2; ++i)
    #pragma unroll
    for (int j = 0; j < 4; ++j) rdacc[i][j] = (f32x4){0.f,0.f,0.f,0.f};

  const int ntiles = Ifull >> 6;
  for (int it = 0; it < ntiles; ++it) {
    const int i0 = it << 6;
    // ---- stage Cg tile [64][128], g = t1 @ Cg^T, silu ----
    for (int li = tid; li < 64*16; li += 256) {
      int r = li >> 4, c = (li & 15) << 3;
      *(short8*)(ldsW + r*SRK + c) = *(const short8*)(pCg + (size_t)(i0+r)*128 + c);
    }
    __syncthreads();
    f32x4 g[2][2];
    #pragma unroll
    for (int i = 0; i < 2; ++i)
      #pragma unroll
      for (int j = 0; j < 2; ++j) g[i][j] = (f32x4){0.f,0.f,0.f,0.f};
    #pragma unroll
    for (int kk = 0; kk < 128; kk += 32) {
      short8 a[2], b[2];
      #pragma unroll
      for (int i = 0; i < 2; ++i)
        a[i] = *(const short8*)(ldsT1 + (mh*32 + i*16 + ln)*SRK + kk + q*8);
      #pragma unroll
      for (int j = 0; j < 2; ++j)
        b[j] = *(const short8*)(ldsW + (nh*32 + j*16 + ln)*SRK + kk + q*8);
      #pragma unroll
      for (int i = 0; i < 2; ++i)
        #pragma unroll
        for (int j = 0; j < 2; ++j) g[i][j] = MF(a[i], b[j], g[i][j]);
    }
    #pragma unroll
    for (int i = 0; i < 2; ++i)
      #pragma unroll
      for (int j = 0; j < 2; ++j)
        #pragma unroll
        for (int r = 0; r < 4; ++r)
          g[i][j][r] = g[i][j][r] / (1.f + expf(-g[i][j][r]));
    __syncthreads();
    // ---- stage Cu tile, u = t2 @ Cu^T, h = g*u -> ldsX[64][SRH] ----
    for (int li = tid; li < 64*16; li += 256) {
      int r = li >> 4, c = (li & 15) << 3;
      *(short8*)(ldsW + r*SRK + c) = *(const short8*)(pCu + (size_t)(i0+r)*128 + c);
    }
    __syncthreads();
    f32x4 u[2][2];
    #pragma unroll
    for (int i = 0; i < 2; ++i)
      #pragma unroll
      for (int j = 0; j < 2; ++j) u[i][j] = (f32x4){0.f,0.f,0.f,0.f};
    #pragma unroll
    for (int kk = 0; kk < 128; kk += 32) {
      short8 a[2], b[2];
      #pragma unroll
      for (int i = 0; i < 2; ++i)
        a[i] = *(const short8*)(ldsT2 + (mh*32 + i*16 + ln)*SRK + kk + q*8);
      #pragma unroll
      for (int j = 0; j < 2; ++j)
        b[j] = *(const short8*)(ldsW + (nh*32 + j*16 + ln)*SRK + kk + q*8);
      #pragma unroll
      for (int i = 0; i < 2; ++i)
        #pragma unroll
        for (int j = 0; j < 2; ++j) u[i][j] = MF(a[i], b[j], u[i][j]);
    }
    #pragma unroll
    for (int i = 0; i < 2; ++i)
      #pragma unroll
      for (int j = 0; j < 2; ++j)
        #pragma unroll
        for (int r = 0; r < 4; ++r)
          ldsX[(mh*32 + i*16 + q*4 + r)*SRH + nh*32 + j*16 + ln] = f2b(g[i][j][r]*u[i][j][r]);
    __syncthreads();
    // ---- stage Rd slice [128][64], rd += h @ Rd^T ----
    for (int li = tid; li < 128*8; li += 256) {
      int r = li >> 3, c = (li & 7) << 3;
      *(short8*)(ldsW + r*SRH + c) = *(const short8*)(pRd + (size_t)r*Ifull + i0 + c);
    }
    __syncthreads();
    #pragma unroll
    for (int kk = 0; kk < 64; kk += 32) {
      short8 a[2], b[4];
      #pragma unroll
      for (int i = 0; i < 2; ++i)
        a[i] = *(const short8*)(ldsX + (mh*32 + i*16 + ln)*SRH + kk + q*8);
      #pragma unroll
      for (int j = 0; j < 4; ++j)
        b[j] = *(const short8*)(ldsW + (nh*64 + j*16 + ln)*SRH + kk + q*8);
      #pragma unroll
      for (int i = 0; i < 2; ++i)
        #pragma unroll
        for (int j = 0; j < 4; ++j) rdacc[i][j] = MF(a[i], b[j], rdacc[i][j]);
    }
    __syncthreads();
  }

  #pragma unroll
  for (int i = 0; i < 2; ++i)
    #pragma unroll
    for (int r = 0; r < 4; ++r) {
      int lr = mh*32 + i*16 + q*4 + r;
      int gs = s0 + lr;
      if (gs < nrows) {
        ushort_t* dst = shm ? (rdsb + (size_t)gs*128) : (rdb + (size_t)(base+gs)*128);
        #pragma unroll
        for (int j = 0; j < 4; ++j)
          dst[nh*64 + j*16 + ln] = f2b(rdacc[i][j][r]);
      }
    }
}

// ---------------------------------------------------------------- out (bf16 MFMA)
// t3 = rd @ Ud^T (LDS bf16), then per 64-col tile: y = t3 @ Cd^T, scale, atomicAdd.
__global__ __launch_bounds__(256) void out_kernel(
    const ushort_t* __restrict__ rdb, const ushort_t* __restrict__ rdsb,
    const ushort_t* __restrict__ Ud, const ushort_t* __restrict__ Cd,
    const ushort_t* __restrict__ sUd, const ushort_t* __restrict__ sCd,
    const int* __restrict__ offA, const int* __restrict__ cntA,
    const int* __restrict__ list_tok, const float* __restrict__ list_w,
    float* __restrict__ out)
{
  __shared__ ushort_t ldsT3[64*SRK];
  __shared__ ushort_t ldsX [64*SRK];
  __shared__ ushort_t ldsW [64*SRK];
  __shared__ int   toks[64];
  __shared__ float wrow[64];

  const int tid = threadIdx.x;
  const int by = blockIdx.y;
  const bool shm = (by == NEXP);
  const int nrows = shm ? T_TOK : cntA[by];
  const int s0 = blockIdx.x * 64;
  if (s0 >= nrows) return;
  const int base = shm ? 0 : offA[by];

  const int lane = tid & 63, wv = tid >> 6;
  const int ln = lane & 15, q = lane >> 4;
  const int mh = wv >> 1, nh = wv & 1;

  if (tid < 64) {
    int sc = s0 + tid; if (sc > nrows-1) sc = nrows-1;
    toks[tid] = shm ? sc : list_tok[base + sc];
    wrow[tid] = shm ? 1.f : list_w[base + sc];
  }
  __syncthreads();

  const ushort_t* rsrc = shm ? rdsb : rdb;
  const ushort_t* pUd = shm ? sUd : Ud + (size_t)by*128*128;
  const ushort_t* pCd = shm ? sCd : Cd + (size_t)by*HD*128;

  for (int li = tid; li < 64*16; li += 256) {
    int r = li >> 4, c = (li & 15) << 3;
    int row = li >> 4; row = s0 + row; if (row > nrows-1) row = nrows-1;
    size_t src_row = shm ? (size_t)row : (size_t)(base + row);
    *(short8*)(ldsX + r*SRK + c) = *(const short8*)(rsrc + src_row*128 + c);
  }
  __syncthreads();
  gemm_AxWT_128(tid, pUd, ldsX, ldsW, ldsT3);

  for (int ct = 0; ct < HD/64; ++ct) {
    for (int li = tid; li < 64*16; li += 256) {
      int r = li >> 4, c = (li & 15) << 3;
      *(short8*)(ldsW + r*SRK + c) = *(const short8*)(pCd + (size_t)(ct*64 + r)*128 + c);
    }
    __syncthreads();
    f32x4 y[2][2];
    #pragma unroll
    for (int i = 0; i < 2; ++i)
      #pragma unroll
      for (int j = 0; j < 2; ++j) y[i][j] = (f32x4){0.f,0.f,0.f,0.f};
    #pragma unroll
    for (int kk = 0; kk < 128; kk += 32) {
      short8 a[2], b[2];
      #pragma unroll
      for (int i = 0; i < 2; ++i)
        a[i] = *(const short8*)(ldsT3 + (mh*32 + i*16 + ln)*SRK + kk + q*8);
      #pragma unroll
      for (int j = 0; j < 2; ++j)
        b[j] = *(const short8*)(ldsW + (nh*32 + j*16 + ln)*SRK + kk + q*8);
      #pragma unroll
      for (int i = 0; i < 2; ++i)
        #pragma unroll
        for (int j = 0; j < 2; ++j) y[i][j] = MF(a[i], b[j], y[i][j]);
    }
    #pragma unroll
    for (int i = 0; i < 2; ++i)
      #pragma unroll
      for (int r = 0; r < 4; ++r) {
        int lr = mh*32 + i*16 + q*4 + r;
        int gs = s0 + lr;
        if (gs < nrows) {
          float wv2 = wrow[lr];
          size_t ob = (size_t)toks[lr]*HD + ct*64;
          #pragma unroll
          for (int j = 0; j < 2; ++j)
            atomicAdd(&out[ob + nh*32 + j*16 + ln], y[i][j][r]*wv2);
        }
      }
    __syncthreads();
  }
}

// ---------------------------------------------------------------- launch
extern "C" void kernel_launch(void* const* d_in, const int* in_sizes, int n_in,
                              void* d_out, int out_size, void* d_ws, size_t ws_size,
                              hipStream_t stream) {
  const float* x    = (const float*)d_in[0];
  const float* gw   = (const float*)d_in[1];
  const float* Rg   = (const float*)d_in[2];
  const float* Ru   = (const float*)d_in[3];
  const float* Rd   = (const float*)d_in[4];
  const float* Ug   = (const float*)d_in[5];
  const float* Cg   = (const float*)d_in[6];
  const float* Uu   = (const float*)d_in[7];
  const float* Cu   = (const float*)d_in[8];
  const float* Ud   = (const float*)d_in[9];
  const float* Cd   = (const float*)d_in[10];
  const float* sRg  = (const float*)d_in[11];
  const float* sUg  = (const float*)d_in[12];
  const float* sCg  = (const float*)d_in[13];
  const float* sRu  = (const float*)d_in[14];
  const float* sUu  = (const float*)d_in[15];
  const float* sCu  = (const float*)d_in[16];
  const float* sRd  = (const float*)d_in[17];
  const float* sUd  = (const float*)d_in[18];
  const float* sCd  = (const float*)d_in[19];
  float* out = (float*)d_out;

  char* w = (char*)d_ws;
  auto alloc = [&](size_t bytes) -> void* {
    void* p = (void*)w; w += (bytes + 255) & ~(size_t)255; return p;
  };
  int*   cnt      = (int*)  alloc(NEXP*sizeof(int));
  int*   offA     = (int*)  alloc((NEXP+1)*sizeof(int));
  int*   fill     = (int*)  alloc(NEXP*sizeof(int));
  int*   topk_idx = (int*)  alloc((size_t)T_TOK*4*sizeof(int));
  float* topk_w   = (float*)alloc((size_t)T_TOK*4*sizeof(float));
  int*   list_tok = (int*)  alloc((size_t)NPAIR*sizeof(int));
  float* list_w   = (float*)alloc((size_t)NPAIR*sizeof(float));
  // bf16 buffers
  ushort_t* xb   = (ushort_t*)alloc((size_t)T_TOK*HD*2);
  ushort_t* Rgb  = (ushort_t*)alloc((size_t)128*HD*2);
  ushort_t* Rub  = (ushort_t*)alloc((size_t)128*HD*2);
  ushort_t* Rdb  = (ushort_t*)alloc((size_t)128*IR*2);
  ushort_t* Ugb  = (ushort_t*)alloc((size_t)NEXP*128*128*2);
  ushort_t* Cgb  = (ushort_t*)alloc((size_t)NEXP*IR*128*2);
  ushort_t* Uub  = (ushort_t*)alloc((size_t)NEXP*128*128*2);
  ushort_t* Cub  = (ushort_t*)alloc((size_t)NEXP*IR*128*2);
  ushort_t* Udb  = (ushort_t*)alloc((size_t)NEXP*128*128*2);
  ushort_t* Cdb  = (ushort_t*)alloc((size_t)NEXP*HD*128*2);
  ushort_t* sRgb = (ushort_t*)alloc((size_t)128*HD*2);
  ushort_t* sUgb = (ushort_t*)alloc((size_t)128*128*2);
  ushort_t* sCgb = (ushort_t*)alloc((size_t)ISH*128*2);
  ushort_t* sRub = (ushort_t*)alloc((size_t)128*HD*2);
  ushort_t* sUub = (ushort_t*)alloc((size_t)128*128*2);
  ushort_t* sCub = (ushort_t*)alloc((size_t)ISH*128*2);
  ushort_t* sRdb = (ushort_t*)alloc((size_t)128*ISH*2);
  ushort_t* sUdb = (ushort_t*)alloc((size_t)128*128*2);
  ushort_t* sCdb = (ushort_t*)alloc((size_t)HD*128*2);
  ushort_t* rg   = (ushort_t*)alloc((size_t)T_TOK*128*2);
  ushort_t* ru   = (ushort_t*)alloc((size_t)T_TOK*128*2);
  ushort_t* sa   = (ushort_t*)alloc((size_t)T_TOK*128*2);
  ushort_t* su   = (ushort_t*)alloc((size_t)T_TOK*128*2);
  ushort_t* rdb  = (ushort_t*)alloc((size_t)NPAIR*128*2);
  ushort_t* rdsb = (ushort_t*)alloc((size_t)T_TOK*128*2);
  (void)ws_size; (void)in_sizes; (void)n_in;

  hipMemsetAsync(cnt,  0, NEXP*sizeof(int), stream);
  hipMemsetAsync(fill, 0, NEXP*sizeof(int), stream);
  hipMemsetAsync(out,  0, (size_t)out_size*sizeof(float), stream);

  auto cvt = [&](const float* s, ushort_t* d, size_t n) {
    int n4 = (int)(n >> 2);
    cvt_kernel<<<(n4 + 255)/256, 256, 0, stream>>>(s, d, n4);
  };
  cvt(x,   xb,  (size_t)T_TOK*HD);
  cvt(Rg,  Rgb, (size_t)128*HD);
  cvt(Ru,  Rub, (size_t)128*HD);
  cvt(Rd,  Rdb, (size_t)128*IR);
  cvt(Ug,  Ugb, (size_t)NEXP*128*128);
  cvt(Cg,  Cgb, (size_t)NEXP*IR*128);
  cvt(Uu,  Uub, (size_t)NEXP*128*128);
  cvt(Cu,  Cub, (size_t)NEXP*IR*128);
  cvt(Ud,  Udb, (size_t)NEXP*128*128);
  cvt(Cd,  Cdb, (size_t)NEXP*HD*128);
  cvt(sRg, sRgb,(size_t)128*HD);
  cvt(sUg, sUgb,(size_t)128*128);
  cvt(sCg, sCgb,(size_t)ISH*128);
  cvt(sRu, sRub,(size_t)128*HD);
  cvt(sUu, sUub,(size_t)128*128);
  cvt(sCu, sCub,(size_t)ISH*128);
  cvt(sRd, sRdb,(size_t)128*ISH);
  cvt(sUd, sUdb,(size_t)128*128);
  cvt(sCd, sCdb,(size_t)HD*128);

  gate_kernel<<<T_TOK, 64, 0, stream>>>(x, gw, topk_idx, topk_w, cnt);
  scan_kernel<<<1, 64, 0, stream>>>(cnt, offA);
  scatter_kernel<<<T_TOK/256, 256, 0, stream>>>(topk_idx, topk_w, offA, fill, list_tok, list_w);
  rproj_kernel<<<dim3(T_TOK/64, 4), 256, 0, stream>>>(xb, Rgb, Rub, sRgb, sRub, rg, ru, sa, su);
  mid_kernel<<<dim3(T_TOK/64, NEXP+1), 256, 0, stream>>>(
      rg, ru, sa, su, Ugb, Cgb, Uub, Cub, Rdb, sUgb, sCgb, sUub, sCub, sRdb,
      offA, cnt, list_tok, rdb, rdsb);
  out_kernel<<<dim3(T_TOK/64, NEXP+1), 256, 0, stream>>>(
      rdb, rdsb, Udb, Cdb, sUdb, sCdb, offA, cnt, list_tok, list_w, out);
}

// Round 3
// 687.332 us; speedup vs baseline: 4.1387x; 1.7401x over previous
//
#include <hip/hip_runtime.h>
#include <math.h>

#define T_TOK 4096
#define HD    2048
#define NEXP  32
#define IR    1408
#define ISH   2816
#define NPAIR (T_TOK*4)
#define SRK   136      // padded bf16 row stride (cold paths only)
#define MTILES 11      // I-tiles (of 64) per chunk: routed 2 chunks, shared 4

typedef unsigned short ushort_t;
typedef __attribute__((ext_vector_type(8))) short    short8;
typedef __attribute__((ext_vector_type(8))) __bf16   bf16x8;
typedef __attribute__((ext_vector_type(4))) float    f32x4;

__device__ __forceinline__ f32x4 MF(short8 a, short8 b, f32x4 c) {
  return __builtin_amdgcn_mfma_f32_16x16x32_bf16(
      __builtin_bit_cast(bf16x8, a), __builtin_bit_cast(bf16x8, b), c, 0, 0, 0);
}
__device__ __forceinline__ ushort_t f2b(float f) {
  unsigned u = __float_as_uint(f);
  unsigned r = (u + 0x7fffu + ((u >> 16) & 1u)) >> 16;   // RNE
  return (ushort_t)r;
}

// async global->LDS 16B; LDS dst must be wave-uniform base (+lane*16 implicit)
__device__ __forceinline__ void gll16(const ushort_t* g, ushort_t* l) {
  __builtin_amdgcn_global_load_lds(
      (const __attribute__((address_space(1))) unsigned int*)(const void*)g,
      (__attribute__((address_space(3))) unsigned int*)(void*)l, 16, 0, 0);
}

// ---- swizzled tile loaders (XOR swizzle: phys chunk = logical ^ (row&mask)) ----
// 64 rows x 128 cols bf16 (16 chunks/row). One instr = 4 rows.
__device__ __forceinline__ void load_64x128_swz(
    const ushort_t* __restrict__ g, size_t gstride, ushort_t* lds, int tid)
{
  const int lane = tid & 63, w = tid >> 6;
  #pragma unroll
  for (int s = 0; s < 4; ++s) {
    int rbase = s*16 + w*4;
    int r = rbase + (lane >> 4);
    int p = lane & 15;
    gll16(g + (size_t)r*gstride + ((p ^ (r & 15)) << 3), lds + rbase*128);
  }
}
// read elem(row r, chunk c of 8hw): lds[r*128 + ((c^(r&15))<<3)]

// 128 rows x 64 cols bf16 (8 chunks/row). One instr = 8 rows.
__device__ __forceinline__ void load_128x64_swz(
    const ushort_t* __restrict__ g, size_t gstride, ushort_t* lds, int tid)
{
  const int lane = tid & 63, w = tid >> 6;
  #pragma unroll
  for (int s = 0; s < 4; ++s) {
    int rbase = s*32 + w*8;
    int r = rbase + (lane >> 3);
    int p = lane & 7;
    gll16(g + (size_t)r*gstride + ((p ^ (r & 7)) << 3), lds + rbase*64);
  }
}
// read elem(row r, chunk c): lds[r*64 + ((c^(r&7))<<3)]

// ---------------------------------------------------------------- fused cvt
#define NSEG 19
struct CvtSegs {
  const float* s[NSEG];
  ushort_t* d[NSEG];
  int n4[NSEG];
  int blk0[NSEG+1];
};
__global__ __launch_bounds__(256) void cvt_all_kernel(CvtSegs cs)
{
  int b = blockIdx.x;
  int k = 0;
  #pragma unroll 1
  while (k+1 < NSEG && b >= cs.blk0[k+1]) ++k;
  int i = (b - cs.blk0[k])*256 + threadIdx.x;
  if (i < cs.n4[k]) {
    float4 v = ((const float4*)cs.s[k])[i];
    ushort4 o; o.x=f2b(v.x); o.y=f2b(v.y); o.z=f2b(v.z); o.w=f2b(v.w);
    ((ushort4*)cs.d[k])[i] = o;
  }
}

// ---------------------------------------------------------------- gate
// 4 tokens/block (4 waves); gw staged through LDS per 128-k chunk.
__global__ __launch_bounds__(256) void gate_kernel(
    const float* __restrict__ x, const float* __restrict__ gw,
    int* __restrict__ topk_idx, float* __restrict__ topk_w, int* __restrict__ cnt)
{
  __shared__ float gws[32*132];
  __shared__ float xs[4*132];
  const int tid = threadIdx.x;
  const int w = tid >> 6, lane = tid & 63;
  const int t0 = blockIdx.x * 4;
  const int e = lane & 31, half = lane >> 5;

  float acc = 0.f;
  for (int ck = 0; ck < HD/128; ++ck) {
    for (int li = tid; li < 1024; li += 256) {        // gw chunk 32x128
      int r = li >> 5, c4 = li & 31;
      *(float4*)(gws + r*132 + c4*4) = *(const float4*)(gw + (size_t)r*HD + ck*128 + c4*4);
    }
    for (int li = tid; li < 128; li += 256) {          // x chunk 4x128
      int r = li >> 5, c4 = li & 31;
      *(float4*)(xs + r*132 + c4*4) = *(const float4*)(x + (size_t)(t0+r)*HD + ck*128 + c4*4);
    }
    __syncthreads();
    #pragma unroll
    for (int k4 = 0; k4 < 16; ++k4) {
      float4 xv = *(const float4*)(xs + w*132 + half*64 + k4*4);
      float4 wv = *(const float4*)(gws + e*132 + half*64 + k4*4);
      acc += xv.x*wv.x + xv.y*wv.y + xv.z*wv.z + xv.w*wv.w;
    }
    __syncthreads();
  }
  float p = acc;
  p += __shfl_down(p, 32);
  float logit = (lane < 32) ? p : -INFINITY;
  float m = logit;
  #pragma unroll
  for (int o = 32; o >= 1; o >>= 1) m = fmaxf(m, __shfl_xor(m, o));
  float ex = (lane < 32) ? expf(logit - m) : 0.f;
  float se = ex;
  #pragma unroll
  for (int o = 32; o >= 1; o >>= 1) se += __shfl_xor(se, o);
  float score = ex / se;

  bool taken = false;
  float selw[4]; int seli[4];
  for (int k = 0; k < 4; ++k) {
    float cur = (lane < 32 && !taken) ? score : -1.f;
    float mm = cur;
    #pragma unroll
    for (int o = 32; o >= 1; o >>= 1) mm = fmaxf(mm, __shfl_xor(mm, o));
    unsigned long long b = __ballot(cur == mm);
    int il = __ffsll(b) - 1;
    if (lane == il) taken = true;
    selw[k] = mm; seli[k] = il;
  }
  float wsum = selw[0]+selw[1]+selw[2]+selw[3] + 1e-20f;
  int t = t0 + w;
  if (lane < 4) {
    topk_idx[t*4+lane] = seli[lane];
    topk_w[t*4+lane]  = selw[lane] / wsum;
    atomicAdd(&cnt[seli[lane]], 1);
  }
}

__global__ void scan_kernel(const int* __restrict__ cnt, int* __restrict__ offA)
{
  if (threadIdx.x == 0) {
    int a = 0;
    for (int e = 0; e < NEXP; ++e) { offA[e] = a; a += cnt[e]; }
    offA[NEXP] = a;
  }
}

__global__ __launch_bounds__(256) void scatter_kernel(
    const int* __restrict__ topk_idx, const float* __restrict__ topk_w,
    const int* __restrict__ offA, int* __restrict__ fill,
    int* __restrict__ list_tok, float* __restrict__ list_w)
{
  int t = blockIdx.x*256 + threadIdx.x;
  if (t >= T_TOK) return;
  #pragma unroll
  for (int k = 0; k < 4; ++k) {
    int e = topk_idx[t*4+k];
    int pos = atomicAdd(&fill[e], 1);
    int s = offA[e] + pos;
    list_tok[s] = t;
    list_w[s]  = topk_w[t*4+k];
  }
}

// ------------------------------------------------- R projections (pipelined)
// Y[T,128] = Xb[T,2048] @ W[128,2048]^T. A via gll dbuf; B-frags from global (L2-hot).
__global__ __launch_bounds__(256) void rproj_kernel(
    const ushort_t* __restrict__ xb,
    const ushort_t* __restrict__ Rg, const ushort_t* __restrict__ Ru,
    const ushort_t* __restrict__ sRg, const ushort_t* __restrict__ sRu,
    ushort_t* __restrict__ rg, ushort_t* __restrict__ ru,
    ushort_t* __restrict__ sa, ushort_t* __restrict__ su)
{
  __shared__ ushort_t abuf[2][64*128];
  const ushort_t* W; ushort_t* Y;
  switch (blockIdx.y) {
    case 0:  W = Rg;  Y = rg; break;
    case 1:  W = Ru;  Y = ru; break;
    case 2:  W = sRg; Y = sa; break;
    default: W = sRu; Y = su; break;
  }
  const int tid = threadIdx.x;
  const int lane = tid & 63, ln = lane & 15, q = lane >> 4;
  const int wv = tid >> 6, mh = wv >> 1, nh = wv & 1;
  const int r0 = blockIdx.x * 64;

  f32x4 acc[2][4];
  #pragma unroll
  for (int i = 0; i < 2; ++i)
    #pragma unroll
    for (int j = 0; j < 4; ++j) acc[i][j] = (f32x4){0.f,0.f,0.f,0.f};

  load_64x128_swz(xb + (size_t)r0*HD, HD, abuf[0], tid);
  for (int kt = 0; kt < 16; ++kt) {
    __syncthreads();                       // abuf[kt&1] ready
    if (kt+1 < 16)
      load_64x128_swz(xb + (size_t)r0*HD + (kt+1)*128, HD, abuf[(kt+1)&1], tid);
    const ushort_t* A = abuf[kt&1];
    #pragma unroll
    for (int c = 0; c < 4; ++c) {
      short8 a[2], b[4];
      #pragma unroll
      for (int i = 0; i < 2; ++i) {
        int rr = mh*32 + i*16 + ln;
        a[i] = *(const short8*)(A + rr*128 + (((c*4+q) ^ (rr&15)) << 3));
      }
      #pragma unroll
      for (int j = 0; j < 4; ++j)
        b[j] = *(const short8*)(W + (size_t)(nh*64 + j*16 + ln)*HD + kt*128 + c*32 + q*8);
      #pragma unroll
      for (int i = 0; i < 2; ++i)
        #pragma unroll
        for (int j = 0; j < 4; ++j) acc[i][j] = MF(a[i], b[j], acc[i][j]);
    }
  }
  #pragma unroll
  for (int i = 0; i < 2; ++i)
    #pragma unroll
    for (int j = 0; j < 4; ++j)
      #pragma unroll
      for (int r = 0; r < 4; ++r)
        Y[(size_t)(r0 + mh*32 + i*16 + q*4 + r)*128 + nh*64 + j*16 + ln] = f2b(acc[i][j][r]);
}

// -------- helper (cold path): acc = A_lds[64][SRK] @ Wg[128][128]^T, C in regs
__device__ __forceinline__ void gemm64x128_regs(
    int tid, const ushort_t* __restrict__ A, const ushort_t* __restrict__ Wg,
    ushort_t* __restrict__ stage, f32x4 acc[2][2][2])
{
  const int lane = tid & 63, ln = lane & 15, q = lane >> 4;
  const int wv = tid >> 6, mh = wv >> 1, nh = wv & 1;
  #pragma unroll
  for (int h = 0; h < 2; ++h)
    #pragma unroll
    for (int i = 0; i < 2; ++i)
      #pragma unroll
      for (int j = 0; j < 2; ++j) acc[h][i][j] = (f32x4){0.f,0.f,0.f,0.f};
  for (int h = 0; h < 2; ++h) {
    for (int li = tid; li < 64*16; li += 256) {
      int r = li >> 4, c = (li & 15) << 3;
      *(short8*)(stage + r*SRK + c) = *(const short8*)(Wg + (size_t)(h*64 + r)*128 + c);
    }
    __syncthreads();
    #pragma unroll
    for (int c = 0; c < 4; ++c) {
      short8 a[2], b[2];
      #pragma unroll
      for (int i = 0; i < 2; ++i)
        a[i] = *(const short8*)(A + (mh*32 + i*16 + ln)*SRK + c*32 + q*8);
      #pragma unroll
      for (int j = 0; j < 2; ++j)
        b[j] = *(const short8*)(stage + (nh*32 + j*16 + ln)*SRK + c*32 + q*8);
      #pragma unroll
      for (int i = 0; i < 2; ++i)
        #pragma unroll
        for (int j = 0; j < 2; ++j) acc[h][i][j] = MF(a[i], b[j], acc[h][i][j]);
    }
    __syncthreads();
  }
}

// ---------------------------------------------------------------- pair_proj
// t1[slot] = rg[tok(slot)] @ Ug_e^T ; t2 = ru @ Uu_e^T ; shared rows direct.
__global__ __launch_bounds__(256) void pair_proj_kernel(
    const ushort_t* __restrict__ rgb, const ushort_t* __restrict__ rub,
    const ushort_t* __restrict__ sab, const ushort_t* __restrict__ sub,
    const ushort_t* __restrict__ Ug, const ushort_t* __restrict__ Uu,
    const ushort_t* __restrict__ sUg, const ushort_t* __restrict__ sUu,
    const int* __restrict__ offA, const int* __restrict__ cntA,
    const int* __restrict__ list_tok,
    ushort_t* __restrict__ t1R, ushort_t* __restrict__ t2R,
    ushort_t* __restrict__ t1S, ushort_t* __restrict__ t2S)
{
  __shared__ ushort_t ldsX[64*SRK];
  __shared__ ushort_t stage[64*SRK];
  __shared__ int toks[64];
  const int tid = threadIdx.x;
  const int by = blockIdx.y;
  const bool shm = (by == NEXP);
  const int nrows = shm ? T_TOK : cntA[by];
  const int s0 = blockIdx.x * 64;
  if (s0 >= nrows) return;
  const int base = shm ? 0 : offA[by];
  const ushort_t* pUg = shm ? sUg : Ug + (size_t)by*128*128;
  const ushort_t* pUu = shm ? sUu : Uu + (size_t)by*128*128;
  const int lane = tid & 63, ln = lane & 15, q = lane >> 4;
  const int wv = tid >> 6, mh = wv >> 1, nh = wv & 1;

  if (tid < 64) {
    int sc = s0 + tid; if (sc > nrows-1) sc = nrows-1;
    toks[tid] = shm ? sc : list_tok[base + sc];
  }
  __syncthreads();

  f32x4 acc[2][2][2];
  // t1
  for (int li = tid; li < 64*16; li += 256) {
    int r = li >> 4, c = (li & 15) << 3;
    const ushort_t* src = shm ? sab : rgb;
    *(short8*)(ldsX + r*SRK + c) = *(const short8*)(src + (size_t)toks[r]*128 + c);
  }
  __syncthreads();
  gemm64x128_regs(tid, ldsX, pUg, stage, acc);
  {
    ushort_t* dst = shm ? t1S : (t1R + (size_t)base*128);
    #pragma unroll
    for (int h = 0; h < 2; ++h)
      #pragma unroll
      for (int i = 0; i < 2; ++i)
        #pragma unroll
        for (int r = 0; r < 4; ++r) {
          int gs = s0 + mh*32 + i*16 + q*4 + r;
          if (gs < nrows) {
            #pragma unroll
            for (int j = 0; j < 2; ++j)
              dst[(size_t)gs*128 + h*64 + nh*32 + j*16 + ln] = f2b(acc[h][i][j][r]);
          }
        }
  }
  // t2
  for (int li = tid; li < 64*16; li += 256) {
    int r = li >> 4, c = (li & 15) << 3;
    const ushort_t* src = shm ? sub : rub;
    *(short8*)(ldsX + r*SRK + c) = *(const short8*)(src + (size_t)toks[r]*128 + c);
  }
  __syncthreads();
  gemm64x128_regs(tid, ldsX, pUu, stage, acc);
  {
    ushort_t* dst = shm ? t2S : (t2R + (size_t)base*128);
    #pragma unroll
    for (int h = 0; h < 2; ++h)
      #pragma unroll
      for (int i = 0; i < 2; ++i)
        #pragma unroll
        for (int r = 0; r < 4; ++r) {
          int gs = s0 + mh*32 + i*16 + q*4 + r;
          if (gs < nrows) {
            #pragma unroll
            for (int j = 0; j < 2; ++j)
              dst[(size_t)gs*128 + h*64 + nh*32 + j*16 + ln] = f2b(acc[h][i][j][r]);
          }
        }
  }
}

// ---------------------------------------------------------------- mid
// grid (64, 33, 4). t1/t2 frags in regs; Cg/Cu/Rd via swizzled gll; 2 barriers/tile.
__global__ __launch_bounds__(256, 2) void mid_kernel(
    const ushort_t* __restrict__ t1R, const ushort_t* __restrict__ t2R,
    const ushort_t* __restrict__ t1S, const ushort_t* __restrict__ t2S,
    const ushort_t* __restrict__ Cg, const ushort_t* __restrict__ Cu,
    const ushort_t* __restrict__ Rd,
    const ushort_t* __restrict__ sCg, const ushort_t* __restrict__ sCu,
    const ushort_t* __restrict__ sRd,
    const int* __restrict__ offA, const int* __restrict__ cntA,
    float* __restrict__ rdR, float* __restrict__ rdS)
{
  __shared__ ushort_t ldsCg[64*128];
  __shared__ ushort_t ldsCu[64*128];
  __shared__ ushort_t ldsRd[128*64];
  __shared__ ushort_t ldsH [64*64];

  const int tid = threadIdx.x;
  const int by = blockIdx.y, bz = blockIdx.z;
  const bool shm = (by == NEXP);
  if (bz >= (shm ? 4 : 2)) return;
  const int nrows = shm ? T_TOK : cntA[by];
  const int s0 = blockIdx.x * 64;
  if (s0 >= nrows) return;
  const int base = shm ? 0 : offA[by];
  const int Ifull = shm ? ISH : IR;
  const ushort_t* pCg = shm ? sCg : Cg + (size_t)by*IR*128;
  const ushort_t* pCu = shm ? sCu : Cu + (size_t)by*IR*128;
  const ushort_t* pRd = shm ? sRd : Rd;

  const int lane = tid & 63, ln = lane & 15, q = lane >> 4;
  const int wv = tid >> 6, mh = wv >> 1, nh = wv & 1;
  const int it0 = bz * MTILES;

  // t1/t2 A-fragments -> registers
  short8 t1f[2][4], t2f[2][4];
  const ushort_t* srcT1 = shm ? t1S : (t1R + (size_t)base*128);
  const ushort_t* srcT2 = shm ? t2S : (t2R + (size_t)base*128);
  #pragma unroll
  for (int i = 0; i < 2; ++i) {
    int r = s0 + mh*32 + i*16 + ln; if (r > nrows-1) r = nrows-1;
    #pragma unroll
    for (int c = 0; c < 4; ++c) {
      t1f[i][c] = *(const short8*)(srcT1 + (size_t)r*128 + c*32 + q*8);
      t2f[i][c] = *(const short8*)(srcT2 + (size_t)r*128 + c*32 + q*8);
    }
  }

  load_64x128_swz(pCg + (size_t)it0*64*128, 128, ldsCg, tid);
  load_64x128_swz(pCu + (size_t)it0*64*128, 128, ldsCu, tid);

  f32x4 rdacc[2][4];
  #pragma unroll
  for (int i = 0; i < 2; ++i)
    #pragma unroll
    for (int j = 0; j < 4; ++j) rdacc[i][j] = (f32x4){0.f,0.f,0.f,0.f};

  __syncthreads();   // Cg/Cu tile 0 ready

  for (int it = 0; it < MTILES; ++it) {
    const int i0 = (it0 + it) * 64;
    // phase A: issue Rd(it); g,u MFMA from regs x ldsCg/Cu; silu; h -> ldsH
    load_128x64_swz(pRd + i0, Ifull, ldsRd, tid);
    f32x4 g[2][2], u[2][2];
    #pragma unroll
    for (int i = 0; i < 2; ++i)
      #pragma unroll
      for (int j = 0; j < 2; ++j) { g[i][j] = (f32x4){0.f,0.f,0.f,0.f}; u[i][j] = (f32x4){0.f,0.f,0.f,0.f}; }
    #pragma unroll
    for (int c = 0; c < 4; ++c) {
      #pragma unroll
      for (int j = 0; j < 2; ++j) {
        int rr = nh*32 + j*16 + ln;
        int off = rr*128 + (((c*4+q) ^ (rr&15)) << 3);
        short8 bg = *(const short8*)(ldsCg + off);
        short8 bu = *(const short8*)(ldsCu + off);
        #pragma unroll
        for (int i = 0; i < 2; ++i) {
          g[i][j] = MF(t1f[i][c], bg, g[i][j]);
          u[i][j] = MF(t2f[i][c], bu, u[i][j]);
        }
      }
    }
    #pragma unroll
    for (int i = 0; i < 2; ++i)
      #pragma unroll
      for (int j = 0; j < 2; ++j)
        #pragma unroll
        for (int r = 0; r < 4; ++r) {
          float gv = g[i][j][r];
          gv = gv / (1.f + __expf(-gv));
          float hv = gv * u[i][j][r];
          int hr = mh*32 + i*16 + q*4 + r;
          int hc = nh*32 + j*16 + ln;
          ldsH[hr*64 + (((hc>>3) ^ (hr&7)) << 3) + (hc&7)] = f2b(hv);
        }
    __syncthreads();   // h visible; Rd(it) landed
    // phase B: issue Cg/Cu(it+1); rd += h @ Rd^T
    if (it+1 < MTILES) {
      load_64x128_swz(pCg + (size_t)(i0+64)*128, 128, ldsCg, tid);
      load_64x128_swz(pCu + (size_t)(i0+64)*128, 128, ldsCu, tid);
    }
    #pragma unroll
    for (int c2 = 0; c2 < 2; ++c2) {
      short8 a[2];
      #pragma unroll
      for (int i = 0; i < 2; ++i) {
        int rr = mh*32 + i*16 + ln;
        a[i] = *(const short8*)(ldsH + rr*64 + (((c2*4+q) ^ (rr&7)) << 3));
      }
      #pragma unroll
      for (int j = 0; j < 4; ++j) {
        int rr = nh*64 + j*16 + ln;
        short8 b = *(const short8*)(ldsRd + rr*64 + (((c2*4+q) ^ (rr&7)) << 3));
        #pragma unroll
        for (int i = 0; i < 2; ++i) rdacc[i][j] = MF(a[i], b, rdacc[i][j]);
      }
    }
    __syncthreads();   // Cg/Cu(it+1) landed; ldsH/ldsRd reads done
  }

  float* dst = shm ? rdS : (rdR + (size_t)base*128);
  #pragma unroll
  for (int i = 0; i < 2; ++i) {
    #pragma unroll
    for (int r = 0; r < 4; ++r) {
      int gs = s0 + mh*32 + i*16 + q*4 + r;
      if (gs < nrows) {
        #pragma unroll
        for (int j = 0; j < 4; ++j)
          atomicAdd(&dst[(size_t)gs*128 + nh*64 + j*16 + ln], rdacc[i][j][r]);
      }
    }
  }
}

// ---------------------------------------------------------------- out
// grid (64, 33, 2). t3 frags in regs; Cd double-buffered via gll; 1 barrier/tile.
__global__ __launch_bounds__(256) void out_kernel(
    const float* __restrict__ rdR, const float* __restrict__ rdS,
    const ushort_t* __restrict__ Ud, const ushort_t* __restrict__ Cd,
    const ushort_t* __restrict__ sUd, const ushort_t* __restrict__ sCd,
    const int* __restrict__ offA, const int* __restrict__ cntA,
    const int* __restrict__ list_tok, const float* __restrict__ list_w,
    float* __restrict__ out)
{
  __shared__ ushort_t smem[3*64*SRK];   // prologue: ldsA | stage | ldsT ; loop: cd0,cd1
  __shared__ int   toks[64];
  __shared__ float wrow[64];
  ushort_t* ldsA  = smem;
  ushort_t* stage = smem + 64*SRK;
  ushort_t* ldsT  = smem + 2*64*SRK;
  ushort_t* cd0   = smem;
  ushort_t* cd1   = smem + 64*128;

  const int tid = threadIdx.x;
  const int by = blockIdx.y;
  const bool shm = (by == NEXP);
  const int nrows = shm ? T_TOK : cntA[by];
  const int s0 = blockIdx.x * 64;
  if (s0 >= nrows) return;
  const int base = shm ? 0 : offA[by];
  const int ct0 = blockIdx.z * 16;
  const ushort_t* pUd = shm ? sUd : Ud + (size_t)by*128*128;
  const ushort_t* pCd = shm ? sCd : Cd + (size_t)by*HD*128;

  const int lane = tid & 63, ln = lane & 15, q = lane >> 4;
  const int wv = tid >> 6, mh = wv >> 1, nh = wv & 1;

  if (tid < 64) {
    int sc = s0 + tid; if (sc > nrows-1) sc = nrows-1;
    toks[tid] = shm ? sc : list_tok[base + sc];
    wrow[tid] = shm ? 1.f : list_w[base + sc];
  }
  // gather rd rows (fp32) -> bf16 ldsA
  for (int li = tid; li < 64*32; li += 256) {
    int r = li >> 5, c4 = li & 31;
    int row = s0 + r; if (row > nrows-1) row = nrows-1;
    const float* src = shm ? (rdS + (size_t)row*128) : (rdR + (size_t)(base+row)*128);
    float4 v = ((const float4*)src)[c4];
    ushort4 o; o.x=f2b(v.x); o.y=f2b(v.y); o.z=f2b(v.z); o.w=f2b(v.w);
    *(ushort4*)(ldsA + r*SRK + c4*4) = o;
  }
  __syncthreads();

  f32x4 acc[2][2][2];
  gemm64x128_regs(tid, ldsA, pUd, stage, acc);
  // C -> ldsT (padded), then extract A-frags
  #pragma unroll
  for (int h = 0; h < 2; ++h)
    #pragma unroll
    for (int i = 0; i < 2; ++i)
      #pragma unroll
      for (int j = 0; j < 2; ++j)
        #pragma unroll
        for (int r = 0; r < 4; ++r)
          ldsT[(mh*32 + i*16 + q*4 + r)*SRK + h*64 + nh*32 + j*16 + ln] = f2b(acc[h][i][j][r]);
  __syncthreads();
  short8 t3f[2][4];
  #pragma unroll
  for (int i = 0; i < 2; ++i)
    #pragma unroll
    for (int c = 0; c < 4; ++c)
      t3f[i][c] = *(const short8*)(ldsT + (mh*32 + i*16 + ln)*SRK + c*32 + q*8);
  __syncthreads();   // smem free for cd buffers

  load_64x128_swz(pCd + (size_t)ct0*64*128, 128, cd0, tid);
  for (int tt = 0; tt < 16; ++tt) {
    __syncthreads();                      // cd[tt&1] ready; prior reads/atomics drained
    ushort_t* cur = (tt & 1) ? cd1 : cd0;
    ushort_t* nxt = (tt & 1) ? cd0 : cd1;
    if (tt+1 < 16)
      load_64x128_swz(pCd + (size_t)(ct0+tt+1)*64*128, 128, nxt, tid);
    f32x4 y[2][2];
    #pragma unroll
    for (int i = 0; i < 2; ++i)
      #pragma unroll
      for (int j = 0; j < 2; ++j) y[i][j] = (f32x4){0.f,0.f,0.f,0.f};
    #pragma unroll
    for (int c = 0; c < 4; ++c) {
      #pragma unroll
      for (int j = 0; j < 2; ++j) {
        int rr = nh*32 + j*16 + ln;
        short8 b = *(const short8*)(cur + rr*128 + (((c*4+q) ^ (rr&15)) << 3));
        #pragma unroll
        for (int i = 0; i < 2; ++i) y[i][j] = MF(t3f[i][c], b, y[i][j]);
      }
    }
    #pragma unroll
    for (int i = 0; i < 2; ++i) {
      #pragma unroll
      for (int r = 0; r < 4; ++r) {
        int lr = mh*32 + i*16 + q*4 + r;
        int gs = s0 + lr;
        if (gs < nrows) {
          float wv2 = wrow[lr];
          size_t ob = (size_t)toks[lr]*HD + (ct0 + tt)*64;
          #pragma unroll
          for (int j = 0; j < 2; ++j)
            atomicAdd(&out[ob + nh*32 + j*16 + ln], y[i][j][r]*wv2);
        }
      }
    }
  }
}

// ---------------------------------------------------------------- launch
extern "C" void kernel_launch(void* const* d_in, const int* in_sizes, int n_in,
                              void* d_out, int out_size, void* d_ws, size_t ws_size,
                              hipStream_t stream) {
  const float* x    = (const float*)d_in[0];
  const float* gw   = (const float*)d_in[1];
  const float* Rg   = (const float*)d_in[2];
  const float* Ru   = (const float*)d_in[3];
  const float* Rd   = (const float*)d_in[4];
  const float* Ug   = (const float*)d_in[5];
  const float* Cg   = (const float*)d_in[6];
  const float* Uu   = (const float*)d_in[7];
  const float* Cu   = (const float*)d_in[8];
  const float* Ud   = (const float*)d_in[9];
  const float* Cd   = (const float*)d_in[10];
  const float* sRg  = (const float*)d_in[11];
  const float* sUg  = (const float*)d_in[12];
  const float* sCg  = (const float*)d_in[13];
  const float* sRu  = (const float*)d_in[14];
  const float* sUu  = (const float*)d_in[15];
  const float* sCu  = (const float*)d_in[16];
  const float* sRd  = (const float*)d_in[17];
  const float* sUd  = (const float*)d_in[18];
  const float* sCd  = (const float*)d_in[19];
  float* out = (float*)d_out;

  char* w = (char*)d_ws;
  auto alloc = [&](size_t bytes) -> void* {
    void* p = (void*)w; w += (bytes + 255) & ~(size_t)255; return p;
  };
  int*   cnt      = (int*)  alloc(NEXP*sizeof(int));
  int*   offA     = (int*)  alloc((NEXP+1)*sizeof(int));
  int*   fill     = (int*)  alloc(NEXP*sizeof(int));
  int*   topk_idx = (int*)  alloc((size_t)T_TOK*4*sizeof(int));
  float* topk_w   = (float*)alloc((size_t)T_TOK*4*sizeof(float));
  int*   list_tok = (int*)  alloc((size_t)NPAIR*sizeof(int));
  float* list_w   = (float*)alloc((size_t)NPAIR*sizeof(float));
  ushort_t* xb   = (ushort_t*)alloc((size_t)T_TOK*HD*2);   // later reused as rdR/rdS (fp32)
  ushort_t* Rgb  = (ushort_t*)alloc((size_t)128*HD*2);
  ushort_t* Rub  = (ushort_t*)alloc((size_t)128*HD*2);
  ushort_t* Rdb  = (ushort_t*)alloc((size_t)128*IR*2);
  ushort_t* Ugb  = (ushort_t*)alloc((size_t)NEXP*128*128*2);
  ushort_t* Cgb  = (ushort_t*)alloc((size_t)NEXP*IR*128*2);
  ushort_t* Uub  = (ushort_t*)alloc((size_t)NEXP*128*128*2);
  ushort_t* Cub  = (ushort_t*)alloc((size_t)NEXP*IR*128*2);
  ushort_t* Udb  = (ushort_t*)alloc((size_t)NEXP*128*128*2);
  ushort_t* Cdb  = (ushort_t*)alloc((size_t)NEXP*HD*128*2);
  ushort_t* sRgb = (ushort_t*)alloc((size_t)128*HD*2);
  ushort_t* sUgb = (ushort_t*)alloc((size_t)128*128*2);
  ushort_t* sCgb = (ushort_t*)alloc((size_t)ISH*128*2);
  ushort_t* sRub = (ushort_t*)alloc((size_t)128*HD*2);
  ushort_t* sUub = (ushort_t*)alloc((size_t)128*128*2);
  ushort_t* sCub = (ushort_t*)alloc((size_t)ISH*128*2);
  ushort_t* sRdb = (ushort_t*)alloc((size_t)128*ISH*2);
  ushort_t* sUdb = (ushort_t*)alloc((size_t)128*128*2);
  ushort_t* sCdb = (ushort_t*)alloc((size_t)HD*128*2);
  ushort_t* rg   = (ushort_t*)alloc((size_t)T_TOK*128*2);
  ushort_t* ru   = (ushort_t*)alloc((size_t)T_TOK*128*2);
  ushort_t* sa   = (ushort_t*)alloc((size_t)T_TOK*128*2);
  ushort_t* su   = (ushort_t*)alloc((size_t)T_TOK*128*2);
  ushort_t* t1R  = (ushort_t*)alloc((size_t)NPAIR*128*2);
  ushort_t* t2R  = (ushort_t*)alloc((size_t)NPAIR*128*2);
  ushort_t* t1S  = (ushort_t*)alloc((size_t)T_TOK*128*2);
  ushort_t* t2S  = (ushort_t*)alloc((size_t)T_TOK*128*2);
  (void)ws_size; (void)in_sizes; (void)n_in;

  // rd accumulators (fp32) alias xb: xb is dead after rproj; memset is stream-ordered after rproj
  float* rdR = (float*)xb;                    // NPAIR*128 fp32 = 8.39 MB
  float* rdS = rdR + (size_t)NPAIR*128;       // T_TOK*128 fp32 = 2.10 MB (total 10.5 <= 16.8 MB)

  hipMemsetAsync(cnt,  0, NEXP*sizeof(int), stream);
  hipMemsetAsync(fill, 0, NEXP*sizeof(int), stream);
  hipMemsetAsync(out,  0, (size_t)out_size*sizeof(float), stream);

  // fused cvt
  CvtSegs cs;
  const float* ss[NSEG] = {x,Rg,Ru,Rd,Ug,Cg,Uu,Cu,Ud,Cd,sRg,sUg,sCg,sRu,sUu,sCu,sRd,sUd,sCd};
  ushort_t* dd[NSEG] = {xb,Rgb,Rub,Rdb,Ugb,Cgb,Uub,Cub,Udb,Cdb,sRgb,sUgb,sCgb,sRub,sUub,sCub,sRdb,sUdb,sCdb};
  size_t nn[NSEG] = {(size_t)T_TOK*HD,(size_t)128*HD,(size_t)128*HD,(size_t)128*IR,
                     (size_t)NEXP*128*128,(size_t)NEXP*IR*128,(size_t)NEXP*128*128,(size_t)NEXP*IR*128,
                     (size_t)NEXP*128*128,(size_t)NEXP*HD*128,(size_t)128*HD,(size_t)128*128,
                     (size_t)ISH*128,(size_t)128*HD,(size_t)128*128,(size_t)ISH*128,
                     (size_t)128*ISH,(size_t)128*128,(size_t)HD*128};
  int tot_blk = 0;
  for (int k = 0; k < NSEG; ++k) {
    cs.s[k] = ss[k]; cs.d[k] = dd[k];
    cs.n4[k] = (int)(nn[k] >> 2);
    cs.blk0[k] = tot_blk;
    tot_blk += (cs.n4[k] + 255) / 256;
  }
  cs.blk0[NSEG] = tot_blk;
  cvt_all_kernel<<<tot_blk, 256, 0, stream>>>(cs);

  gate_kernel<<<T_TOK/4, 256, 0, stream>>>(x, gw, topk_idx, topk_w, cnt);
  scan_kernel<<<1, 64, 0, stream>>>(cnt, offA);
  scatter_kernel<<<T_TOK/256, 256, 0, stream>>>(topk_idx, topk_w, offA, fill, list_tok, list_w);
  rproj_kernel<<<dim3(T_TOK/64, 4), 256, 0, stream>>>(xb, Rgb, Rub, sRgb, sRub, rg, ru, sa, su);
  hipMemsetAsync(rdR, 0, (size_t)(NPAIR + T_TOK)*128*sizeof(float), stream);   // after rproj: xb dead
  pair_proj_kernel<<<dim3(64, NEXP+1), 256, 0, stream>>>(
      rg, ru, sa, su, Ugb, Uub, sUgb, sUub, offA, cnt, list_tok, t1R, t2R, t1S, t2S);
  mid_kernel<<<dim3(64, NEXP+1, 4), 256, 0, stream>>>(
      t1R, t2R, t1S, t2S, Cgb, Cub, Rdb, sCgb, sCub, sRdb, offA, cnt, rdR, rdS);
  out_kernel<<<dim3(64, NEXP+1, 2), 256, 0, stream>>>(
      rdR, rdS, Udb, Cdb, sUdb, sCdb, offA, cnt, list_tok, list_w, out);
}